// Round 1
// baseline (253.986 us; speedup 1.0000x reference)
//
#include <hip/hip_runtime.h>
#include <math.h>

#define T_    10
#define NB_   10
#define C1_   20            // 2*NB
#define SX_   1200
#define OX_   302
#define S2_   (OX_*OX_)     // 91204
#define NP_   300           // pooled interior size
#define ND_   5
#define FLAT_ (NB_*S2_)     // 912040
#define NBLK_FC1 512

typedef float f4 __attribute__((ext_vector_type(4), aligned(4)));

// Fill x5 border pixels (value = conv2_b[channel]) into dyn buffer (all t, ch 0..4)
// and feat stat channels (ch 5..9).
__global__ __launch_bounds__(256) void k_border(const float* __restrict__ b2,
                                                float* __restrict__ dynb,
                                                float* __restrict__ feat) {
    int s = blockIdx.x * 256 + threadIdx.x;
    if (s >= S2_) return;
    int ox = s / OX_, oy = s % OX_;
    if (ox != 0 && ox != OX_ - 1 && oy != 0 && oy != OX_ - 1) return;
#pragma unroll
    for (int d = 0; d < ND_; ++d) {
        float v = b2[d];
#pragma unroll
        for (int t = 0; t < T_; ++t) dynb[(t * ND_ + d) * S2_ + s] = v;
    }
#pragma unroll
    for (int c = 0; c < ND_; ++c) feat[(ND_ + c) * S2_ + s] = b2[ND_ + c];
}

// Fused: 1x1 conv1 (+zero-pad semantics) -> 4x4 maxpool -> 1x1 conv2 (interior).
// One thread per (t, pooled px, pooled py).
__global__ __launch_bounds__(256) void k_convpool(const float* __restrict__ x,
                                                  const float* __restrict__ w1,
                                                  const float* __restrict__ b1,
                                                  const float* __restrict__ w2,
                                                  const float* __restrict__ b2,
                                                  float* __restrict__ dynb,
                                                  float* __restrict__ feat) {
    int py = blockIdx.x * 64 + threadIdx.x;   // 0..319, mask to <300
    int px = blockIdx.y * 4 + threadIdx.y;    // 0..299
    int t  = blockIdx.z;                      // 0..9
    if (py >= NP_) return;

    float pool[C1_];
#pragma unroll
    for (int o = 0; o < C1_; ++o) pool[o] = -3.0e38f;

    // pooled block covers padded rows 4px..4px+3 -> original 4px-1..4px+2 (row -1 = pad)
    int c0 = (py > 0) ? 4 * py - 1 : 0;       // first loaded original column
    int rs = (px > 0) ? 4 * px - 1 : 0;
    int re = 4 * px + 2;
    const float* xt = x + (size_t)t * NB_ * SX_ * SX_;

    for (int row = rs; row <= re; ++row) {
        f4 xv[NB_];
#pragma unroll
        for (int c = 0; c < NB_; ++c)
            xv[c] = *(const f4*)(xt + ((size_t)c * SX_ + row) * SX_ + c0);
#pragma unroll
        for (int o = 0; o < C1_; ++o) {
            float bb = b1[o];
            float h0 = bb, h1 = bb, h2 = bb, h3 = bb;
#pragma unroll
            for (int c = 0; c < NB_; ++c) {
                float w = w1[o * NB_ + c];
                h0 = fmaf(w, xv[c].x, h0);
                h1 = fmaf(w, xv[c].y, h1);
                h2 = fmaf(w, xv[c].z, h2);
                h3 = fmaf(w, xv[c].w, h3);
            }
            float m = fmaxf(fmaxf(h0, h1), h2);
            // py==0: loaded cols 0..3 map to block positions 1..3 (elem 3 = next block) -> exclude h3
            m = fmaxf(m, (py > 0) ? h3 : -3.0e38f);
            pool[o] = fmaxf(pool[o], m);
        }
    }
    if (px == 0 || py == 0) {                 // pad positions contribute conv1 bias
#pragma unroll
        for (int o = 0; o < C1_; ++o) pool[o] = fmaxf(pool[o], b1[o]);
    }

    int s = (px + 1) * OX_ + (py + 1);
    float out[NB_];
#pragma unroll
    for (int o2 = 0; o2 < NB_; ++o2) {
        float a = b2[o2];
#pragma unroll
        for (int o = 0; o < C1_; ++o) a = fmaf(w2[o2 * C1_ + o], pool[o], a);
        out[o2] = a;
    }
#pragma unroll
    for (int d = 0; d < ND_; ++d) dynb[(t * ND_ + d) * S2_ + s] = out[d];
    if (t == T_ - 1) {
#pragma unroll
        for (int c = 0; c < ND_; ++c) feat[(ND_ + c) * S2_ + s] = out[ND_ + c];
    }
}

// Scrambled-reshape scalar LSTM: sequence p in [0,91204), feature d in [0,5).
// input(tt) = dynb[p*50 + tt*5 + d]; output -> feat[d*S2 + p].
__global__ __launch_bounds__(256) void k_lstm(const float* __restrict__ dynb,
                                              const float* __restrict__ w_ih,
                                              const float* __restrict__ w_hh,
                                              const float* __restrict__ b_ih,
                                              const float* __restrict__ b_hh,
                                              float* __restrict__ feat) {
    int i = blockIdx.x * 256 + threadIdx.x;
    if (i >= S2_ * ND_) return;
    int p = i / ND_, d = i - p * ND_;

    float wi[4], wh[4], bb[4];
#pragma unroll
    for (int g = 0; g < 4; ++g) {
        wi[g] = w_ih[d * 4 + g];
        wh[g] = w_hh[d * 4 + g];
        bb[g] = b_ih[d * 4 + g] + b_hh[d * 4 + g];
    }
    float h = 0.f, cc = 0.f;
    for (int tt = 0; tt < T_; ++tt) {
        float xt = dynb[p * (T_ * ND_) + tt * ND_ + d];
        float g0 = fmaf(xt, wi[0], fmaf(h, wh[0], bb[0]));
        float g1 = fmaf(xt, wi[1], fmaf(h, wh[1], bb[1]));
        float g2 = fmaf(xt, wi[2], fmaf(h, wh[2], bb[2]));
        float g3 = fmaf(xt, wi[3], fmaf(h, wh[3], bb[3]));
        float ig = 1.f / (1.f + expf(-g0));
        float fg = 1.f / (1.f + expf(-g1));
        float gg = tanhf(g2);
        float og = 1.f / (1.f + expf(-g3));
        cc = fg * cc + ig * gg;
        h  = og * tanhf(cc);
    }
    feat[d * S2_ + p] = h;
}

// fc1 partial GEMV: each block accumulates 64 outputs over a strided i4-range.
__global__ __launch_bounds__(256) void k_fc1(const float* __restrict__ feat,
                                             const float* __restrict__ w,
                                             float* __restrict__ partial) {
    __shared__ float red[4 * 64];
    int tid = threadIdx.x;
    float acc[64];
#pragma unroll
    for (int j = 0; j < 64; ++j) acc[j] = 0.f;
    const int NI4 = FLAT_ / 4;   // 228010
    for (int i4 = blockIdx.x * 256 + tid; i4 < NI4; i4 += NBLK_FC1 * 256) {
        f4 f = *(const f4*)(feat + (size_t)i4 * 4);
#pragma unroll
        for (int j = 0; j < 64; ++j) {
            f4 wv = *(const f4*)(w + (size_t)j * FLAT_ + (size_t)i4 * 4);
            acc[j] = fmaf(wv.x, f.x, acc[j]);
            acc[j] = fmaf(wv.y, f.y, acc[j]);
            acc[j] = fmaf(wv.z, f.z, acc[j]);
            acc[j] = fmaf(wv.w, f.w, acc[j]);
        }
    }
    int lane = tid & 63, wid = tid >> 6;
#pragma unroll
    for (int j = 0; j < 64; ++j) {
        float v = acc[j];
#pragma unroll
        for (int off = 32; off >= 1; off >>= 1) v += __shfl_xor(v, off, 64);
        if (lane == 0) red[wid * 64 + j] = v;
    }
    __syncthreads();
    if (tid < 64) {
        float s = red[tid] + red[64 + tid] + red[128 + tid] + red[192 + tid];
        partial[blockIdx.x * 64 + tid] = s;
    }
}

// Final reduce + fc2/relu/fc3/fc4 -> 3 outputs. Single block.
__global__ __launch_bounds__(256) void k_head(const float* __restrict__ partial,
                                              const float* __restrict__ fc1_b,
                                              const float* __restrict__ fc2_w,
                                              const float* __restrict__ fc2_b,
                                              const float* __restrict__ fc3_w,
                                              const float* __restrict__ fc3_b,
                                              const float* __restrict__ fc4_w,
                                              const float* __restrict__ fc4_b,
                                              float* __restrict__ out) {
    __shared__ float r4[256];
    __shared__ float y1[64], y2[64], y3[16];
    int tid = threadIdx.x;
    int j = tid & 63, q = tid >> 6;
    float s = 0.f;
    for (int b = q; b < NBLK_FC1; b += 4) s += partial[b * 64 + j];
    r4[tid] = s;
    __syncthreads();
    if (tid < 64)
        y1[tid] = r4[tid] + r4[64 + tid] + r4[128 + tid] + r4[192 + tid] + fc1_b[tid];
    __syncthreads();
    if (tid < 64) {
        float a = fc2_b[tid];
#pragma unroll
        for (int k = 0; k < 64; ++k) a = fmaf(fc2_w[tid * 64 + k], y1[k], a);
        y2[tid] = fmaxf(a, 0.f);   // relu AFTER fc2 (per reference)
    }
    __syncthreads();
    if (tid < 16) {
        float a = fc3_b[tid];
#pragma unroll
        for (int k = 0; k < 64; ++k) a = fmaf(fc3_w[tid * 64 + k], y2[k], a);
        y3[tid] = a;
    }
    __syncthreads();
    if (tid < 3) {
        float a = fc4_b[tid];
#pragma unroll
        for (int k = 0; k < 16; ++k) a = fmaf(fc4_w[tid * 16 + k], y3[k], a);
        out[tid] = a;
    }
}

extern "C" void kernel_launch(void* const* d_in, const int* in_sizes, int n_in,
                              void* d_out, int out_size, void* d_ws, size_t ws_size,
                              hipStream_t stream) {
    const float* x     = (const float*)d_in[0];
    const float* w1    = (const float*)d_in[1];
    const float* b1    = (const float*)d_in[2];
    const float* w2    = (const float*)d_in[3];
    const float* b2    = (const float*)d_in[4];
    const float* w_ih  = (const float*)d_in[5];
    const float* w_hh  = (const float*)d_in[6];
    const float* b_ih  = (const float*)d_in[7];
    const float* b_hh  = (const float*)d_in[8];
    const float* fc1_w = (const float*)d_in[9];
    const float* fc1_b = (const float*)d_in[10];
    const float* fc2_w = (const float*)d_in[11];
    const float* fc2_b = (const float*)d_in[12];
    const float* fc3_w = (const float*)d_in[13];
    const float* fc3_b = (const float*)d_in[14];
    const float* fc4_w = (const float*)d_in[15];
    const float* fc4_b = (const float*)d_in[16];

    float* ws      = (float*)d_ws;
    float* dynb    = ws;                         // [10][5][91204] = 4,560,200 f
    float* feat    = ws + (size_t)T_ * ND_ * S2_; // [10][91204]    =   912,040 f
    float* partial = feat + FLAT_;               // [512][64]      =    32,768 f

    hipLaunchKernelGGL(k_border, dim3((S2_ + 255) / 256), dim3(256), 0, stream,
                       b2, dynb, feat);
    hipLaunchKernelGGL(k_convpool, dim3(5, 75, T_), dim3(64, 4), 0, stream,
                       x, w1, b1, w2, b2, dynb, feat);
    hipLaunchKernelGGL(k_lstm, dim3((S2_ * ND_ + 255) / 256), dim3(256), 0, stream,
                       dynb, w_ih, w_hh, b_ih, b_hh, feat);
    hipLaunchKernelGGL(k_fc1, dim3(NBLK_FC1), dim3(256), 0, stream,
                       feat, fc1_w, partial);
    hipLaunchKernelGGL(k_head, dim3(1), dim3(256), 0, stream,
                       partial, fc1_b, fc2_w, fc2_b, fc3_w, fc3_b, fc4_w, fc4_b,
                       (float*)d_out);
}

// Round 2
// 242.860 us; speedup vs baseline: 1.0458x; 1.0458x over previous
//
#include <hip/hip_runtime.h>
#include <math.h>

#define T_    10
#define NB_   10
#define C1_   20            // 2*NB
#define SX_   1200
#define OX_   302
#define S2_   (OX_*OX_)     // 91204
#define NP_   300           // pooled interior size
#define ND_   5
#define FLAT_ (NB_*S2_)     // 912040
#define NBLK_FC1 512

typedef float f4 __attribute__((ext_vector_type(4)));   // 16B-aligned

// Fill x5 border pixels (value = conv2_b[channel]) into dyn buffer (all t, ch 0..4)
// and feat stat channels (ch 5..9).
__global__ __launch_bounds__(256) void k_border(const float* __restrict__ b2,
                                                float* __restrict__ dynb,
                                                float* __restrict__ feat) {
    int s = blockIdx.x * 256 + threadIdx.x;
    if (s >= S2_) return;
    int ox = s / OX_, oy = s % OX_;
    if (ox != 0 && ox != OX_ - 1 && oy != 0 && oy != OX_ - 1) return;
#pragma unroll
    for (int d = 0; d < ND_; ++d) {
        float v = b2[d];
#pragma unroll
        for (int t = 0; t < T_; ++t) dynb[(t * ND_ + d) * S2_ + s] = v;
    }
#pragma unroll
    for (int c = 0; c < ND_; ++c) feat[(ND_ + c) * S2_ + s] = b2[ND_ + c];
}

// Fused: 1x1 conv1 (+zero-pad) -> 4x4 maxpool -> 1x1 conv2 (interior).
// ALIGNED loads: lane l loads f4 at cols [4*(obase-1+l), +4). Output k (=lane)
// combines own col3 (pool3) with lane k+1's cols0..2 (pool012) via shfl_down.
// 63 outputs per 64-lane wave. No early returns (shuffle needs all lanes).
__global__ __launch_bounds__(256) void k_convpool(const float* __restrict__ x,
                                                  const float* __restrict__ w1,
                                                  const float* __restrict__ b1,
                                                  const float* __restrict__ w2,
                                                  const float* __restrict__ b2,
                                                  float* __restrict__ dynb,
                                                  float* __restrict__ feat) {
    const int lane  = threadIdx.x;                 // 0..63
    const int obase = blockIdx.x * 63;             // 0,63,126,189,252
    const int px    = blockIdx.y * 4 + threadIdx.y; // 0..299
    const int t     = blockIdx.z;

    const int lc  = 4 * (obase - 1 + lane);        // this lane's column base
    const int lcc = lc < 0 ? 0 : (lc > SX_ - 4 ? SX_ - 4 : lc);
    const bool m3valid = (lc >= 0);

    float pool012[C1_], pool3[C1_];
#pragma unroll
    for (int o = 0; o < C1_; ++o) { pool012[o] = -3.0e38f; pool3[o] = -3.0e38f; }

    const int rs = (px > 0) ? 4 * px - 1 : 0;
    const int re = 4 * px + 2;
    const float* xt = x + (size_t)t * NB_ * SX_ * SX_;

    for (int row = rs; row <= re; ++row) {
        f4 xv[NB_];
#pragma unroll
        for (int c = 0; c < NB_; ++c)
            xv[c] = *(const f4*)(xt + ((size_t)c * SX_ + row) * SX_ + lcc);
#pragma unroll
        for (int o = 0; o < C1_; ++o) {
            float bb = b1[o];
            float h0 = bb, h1 = bb, h2 = bb, h3 = bb;
#pragma unroll
            for (int c = 0; c < NB_; ++c) {
                float w = w1[o * NB_ + c];
                h0 = fmaf(w, xv[c].x, h0);
                h1 = fmaf(w, xv[c].y, h1);
                h2 = fmaf(w, xv[c].z, h2);
                h3 = fmaf(w, xv[c].w, h3);
            }
            pool012[o] = fmaxf(pool012[o], fmaxf(fmaxf(h0, h1), h2));
            pool3[o]   = fmaxf(pool3[o], h3);
        }
    }

    const int py = obase + lane;                   // output index this lane produces
    const bool edge = (px == 0) | (py == 0);
    float pool[C1_];
#pragma unroll
    for (int o = 0; o < C1_; ++o) {
        float m3    = m3valid ? pool3[o] : -3.0e38f;
        float other = __shfl_down(pool012[o], 1, 64);   // lane k+1's cols 0..2
        float p = fmaxf(m3, other);
        if (edge) p = fmaxf(p, b1[o]);             // zero-pad positions -> conv1 bias
        pool[o] = p;
    }

    if (lane < 63 && py < NP_) {
        int s = (px + 1) * OX_ + (py + 1);
        float out[NB_];
#pragma unroll
        for (int o2 = 0; o2 < NB_; ++o2) {
            float a = b2[o2];
#pragma unroll
            for (int o = 0; o < C1_; ++o) a = fmaf(w2[o2 * C1_ + o], pool[o], a);
            out[o2] = a;
        }
#pragma unroll
        for (int d = 0; d < ND_; ++d) dynb[(t * ND_ + d) * S2_ + s] = out[d];
        if (t == T_ - 1) {
#pragma unroll
            for (int c = 0; c < ND_; ++c) feat[(ND_ + c) * S2_ + s] = out[ND_ + c];
        }
    }
}

// Scrambled-reshape scalar LSTM: sequence p in [0,91204), feature d in [0,5).
__global__ __launch_bounds__(256) void k_lstm(const float* __restrict__ dynb,
                                              const float* __restrict__ w_ih,
                                              const float* __restrict__ w_hh,
                                              const float* __restrict__ b_ih,
                                              const float* __restrict__ b_hh,
                                              float* __restrict__ feat) {
    int i = blockIdx.x * 256 + threadIdx.x;
    if (i >= S2_ * ND_) return;
    int p = i / ND_, d = i - p * ND_;

    float wi[4], wh[4], bb[4];
#pragma unroll
    for (int g = 0; g < 4; ++g) {
        wi[g] = w_ih[d * 4 + g];
        wh[g] = w_hh[d * 4 + g];
        bb[g] = b_ih[d * 4 + g] + b_hh[d * 4 + g];
    }
    float h = 0.f, cc = 0.f;
    for (int tt = 0; tt < T_; ++tt) {
        float xt = dynb[p * (T_ * ND_) + tt * ND_ + d];
        float g0 = fmaf(xt, wi[0], fmaf(h, wh[0], bb[0]));
        float g1 = fmaf(xt, wi[1], fmaf(h, wh[1], bb[1]));
        float g2 = fmaf(xt, wi[2], fmaf(h, wh[2], bb[2]));
        float g3 = fmaf(xt, wi[3], fmaf(h, wh[3], bb[3]));
        float ig = 1.f / (1.f + expf(-g0));
        float fg = 1.f / (1.f + expf(-g1));
        float gg = tanhf(g2);
        float og = 1.f / (1.f + expf(-g3));
        cc = fg * cc + ig * gg;
        h  = og * tanhf(cc);
    }
    feat[d * S2_ + p] = h;
}

// fc1 partial GEMV: grid (512, 2); block (bx,jy) accumulates 32 outputs
// (j = jy*32 + 0..31) over a strided i4-range. acc[32] keeps VGPR sane.
__global__ __launch_bounds__(256) void k_fc1(const float* __restrict__ feat,
                                             const float* __restrict__ w,
                                             float* __restrict__ partial) {
    __shared__ float red[4][32];
    int tid = threadIdx.x;
    int jbase = blockIdx.y * 32;
    float acc[32];
#pragma unroll
    for (int j = 0; j < 32; ++j) acc[j] = 0.f;
    const int NI4 = FLAT_ / 4;   // 228010
    const float* wb = w + (size_t)jbase * FLAT_;
    for (int i4 = blockIdx.x * 256 + tid; i4 < NI4; i4 += NBLK_FC1 * 256) {
        f4 f = *(const f4*)(feat + (size_t)i4 * 4);
#pragma unroll
        for (int j = 0; j < 32; ++j) {
            f4 wv = *(const f4*)(wb + (size_t)j * FLAT_ + (size_t)i4 * 4);
            acc[j] = fmaf(wv.x, f.x, acc[j]);
            acc[j] = fmaf(wv.y, f.y, acc[j]);
            acc[j] = fmaf(wv.z, f.z, acc[j]);
            acc[j] = fmaf(wv.w, f.w, acc[j]);
        }
    }
    int lane = tid & 63, wid = tid >> 6;
#pragma unroll
    for (int j = 0; j < 32; ++j) {
        float v = acc[j];
#pragma unroll
        for (int off = 32; off >= 1; off >>= 1) v += __shfl_xor(v, off, 64);
        if (lane == 0) red[wid][j] = v;
    }
    __syncthreads();
    if (tid < 32) {
        float s = red[0][tid] + red[1][tid] + red[2][tid] + red[3][tid];
        partial[blockIdx.x * 64 + jbase + tid] = s;
    }
}

// Final reduce + fc2/relu/fc3/fc4 -> 3 outputs. Single block.
__global__ __launch_bounds__(256) void k_head(const float* __restrict__ partial,
                                              const float* __restrict__ fc1_b,
                                              const float* __restrict__ fc2_w,
                                              const float* __restrict__ fc2_b,
                                              const float* __restrict__ fc3_w,
                                              const float* __restrict__ fc3_b,
                                              const float* __restrict__ fc4_w,
                                              const float* __restrict__ fc4_b,
                                              float* __restrict__ out) {
    __shared__ float r4[256];
    __shared__ float y1[64], y2[64], y3[16];
    int tid = threadIdx.x;
    int j = tid & 63, q = tid >> 6;
    float s = 0.f;
    for (int b = q; b < NBLK_FC1; b += 4) s += partial[b * 64 + j];
    r4[tid] = s;
    __syncthreads();
    if (tid < 64)
        y1[tid] = r4[tid] + r4[64 + tid] + r4[128 + tid] + r4[192 + tid] + fc1_b[tid];
    __syncthreads();
    if (tid < 64) {
        float a = fc2_b[tid];
#pragma unroll
        for (int k = 0; k < 64; ++k) a = fmaf(fc2_w[tid * 64 + k], y1[k], a);
        y2[tid] = fmaxf(a, 0.f);   // relu AFTER fc2 (per reference)
    }
    __syncthreads();
    if (tid < 16) {
        float a = fc3_b[tid];
#pragma unroll
        for (int k = 0; k < 64; ++k) a = fmaf(fc3_w[tid * 64 + k], y2[k], a);
        y3[tid] = a;
    }
    __syncthreads();
    if (tid < 3) {
        float a = fc4_b[tid];
#pragma unroll
        for (int k = 0; k < 16; ++k) a = fmaf(fc4_w[tid * 16 + k], y3[k], a);
        out[tid] = a;
    }
}

extern "C" void kernel_launch(void* const* d_in, const int* in_sizes, int n_in,
                              void* d_out, int out_size, void* d_ws, size_t ws_size,
                              hipStream_t stream) {
    const float* x     = (const float*)d_in[0];
    const float* w1    = (const float*)d_in[1];
    const float* b1    = (const float*)d_in[2];
    const float* w2    = (const float*)d_in[3];
    const float* b2    = (const float*)d_in[4];
    const float* w_ih  = (const float*)d_in[5];
    const float* w_hh  = (const float*)d_in[6];
    const float* b_ih  = (const float*)d_in[7];
    const float* b_hh  = (const float*)d_in[8];
    const float* fc1_w = (const float*)d_in[9];
    const float* fc1_b = (const float*)d_in[10];
    const float* fc2_w = (const float*)d_in[11];
    const float* fc2_b = (const float*)d_in[12];
    const float* fc3_w = (const float*)d_in[13];
    const float* fc3_b = (const float*)d_in[14];
    const float* fc4_w = (const float*)d_in[15];
    const float* fc4_b = (const float*)d_in[16];

    float* ws      = (float*)d_ws;
    float* dynb    = ws;                          // [10][5][91204]
    float* feat    = ws + (size_t)T_ * ND_ * S2_; // [10][91204]
    float* partial = feat + FLAT_;                // [512][64]

    hipLaunchKernelGGL(k_border, dim3((S2_ + 255) / 256), dim3(256), 0, stream,
                       b2, dynb, feat);
    hipLaunchKernelGGL(k_convpool, dim3(5, 75, T_), dim3(64, 4), 0, stream,
                       x, w1, b1, w2, b2, dynb, feat);
    hipLaunchKernelGGL(k_lstm, dim3((S2_ * ND_ + 255) / 256), dim3(256), 0, stream,
                       dynb, w_ih, w_hh, b_ih, b_hh, feat);
    hipLaunchKernelGGL(k_fc1, dim3(NBLK_FC1, 2), dim3(256), 0, stream,
                       feat, fc1_w, partial);
    hipLaunchKernelGGL(k_head, dim3(1), dim3(256), 0, stream,
                       partial, fc1_b, fc2_w, fc2_b, fc3_w, fc3_b, fc4_w, fc4_b,
                       (float*)d_out);
}